// Round 8
// baseline (125.766 us; speedup 1.0000x reference)
//
#include <hip/hip_runtime.h>

#define NPTS 2048
#define KNBR 16

typedef __attribute__((ext_vector_type(8))) short bf16x8;
typedef __attribute__((ext_vector_type(4))) float f32x4;
union U8 { bf16x8 v; unsigned u[4]; };

// gfx950 packed f32->bf16 (RNE)
static __device__ __forceinline__ unsigned pk2(float lo, float hi) {
    unsigned r;
    asm("v_cvt_pk_bf16_f32 %0, %1, %2" : "=v"(r) : "v"(lo), "v"(hi));
    return r;
}

// tanh-approx gelu (sigmoid form) — R5-proven __expf variant
static __device__ __forceinline__ float gelu(float x) {
    float x2 = x * x;
    float u  = x * fmaf(x2, 0.044715f, 1.0f);
    float e  = __expf(u * -1.5957691216057308f);
    return x * __builtin_amdgcn_rcpf(1.0f + e);
}

// LDS layout (shorts):
//   [0,20480)      w1f : W1 rows 128..287 (5 ks, rows>=259 zero), f=nt*5+ks
//   [20480,36864)  w2f : W2 (4 ks), f=nt*4+ks
//   [36864,53248)  w1a : W1 rows 0..127 (phase-B only), f=nt*4+ks
//   [36864,57344)  staging (overlays w1a after barrier):
//                  16 waves x [2 nodes][16 m][STG=40]
//   [57344,73728)  base: 16 waves x 4 nodes x 128 fp32
#define STG 40
#define LDS_BYTES 147456

__global__ __launch_bounds__(1024, 4) void edgeconv_fused(
    const float* __restrict__ h, const float* __restrict__ pos,
    const int* __restrict__ idx,
    const float* __restrict__ W1, const float* __restrict__ W2,
    const float* __restrict__ b1, const float* __restrict__ b2,
    const float* __restrict__ gamma, const float* __restrict__ beta,
    float* __restrict__ out)
{
    extern __shared__ short lds[];
    float* ldsF = (float*)lds;
    const int tid = threadIdx.x, wave = tid >> 6, lane = tid & 63;
    const int quad = lane >> 4, lm = lane & 15;

    // ---- phase A: swizzle weights (global fp32 -> LDS bf16 B-fragments) ----
    for (int c = tid; c < 6656; c += 1024) {
        const int l = c & 63, fi = c >> 6;
        const int lrow = (l >> 4) * 8, lcol = l & 15;
        U8 t;
        if (fi < 40) {                        // w1f (W1 rows 128..287)
            int ks = fi % 5, nt = fi / 5;
            int row0 = 128 + ks * 32 + lrow, col = nt * 16 + lcol;
            #pragma unroll
            for (int p = 0; p < 4; ++p) {
                int r0 = row0 + 2 * p;
                float v0 = (r0     < 259) ? W1[r0 * 128 + col]       : 0.f;
                float v1 = (r0 + 1 < 259) ? W1[(r0 + 1) * 128 + col] : 0.f;
                t.u[p] = pk2(v0, v1);
            }
        } else if (fi < 72) {                 // w2f
            int f2 = fi - 40, ks = f2 & 3, nt = f2 >> 2;
            int row0 = ks * 32 + lrow, col = nt * 16 + lcol;
            #pragma unroll
            for (int p = 0; p < 4; ++p)
                t.u[p] = pk2(W2[(row0 + 2*p) * 128 + col],
                             W2[(row0 + 2*p + 1) * 128 + col]);
        } else {                              // w1a (W1 rows 0..127)
            int f2 = fi - 72, ks = f2 & 3, nt = f2 >> 2;
            int row0 = ks * 32 + lrow, col = nt * 16 + lcol;
            #pragma unroll
            for (int p = 0; p < 4; ++p)
                t.u[p] = pk2(W1[(row0 + 2*p) * 128 + col],
                             W1[(row0 + 2*p + 1) * 128 + col]);
        }
        ((bf16x8*)lds)[c] = t.v;
    }

    float b1v[8], b2v[8];
    #pragma unroll
    for (int nt = 0; nt < 8; ++nt) {
        b1v[nt] = b1[nt * 16 + lm];
        b2v[nt] = b2[nt * 16 + lm];
    }
    const float gv0 = gamma[(quad * 2) * 16 + lm];
    const float gv1 = gamma[(quad * 2 + 1) * 16 + lm];
    const float be0 = beta[(quad * 2) * 16 + lm];
    const float be1 = beta[(quad * 2 + 1) * 16 + lm];

    __syncthreads();

    const bf16x8* w1frag  = (const bf16x8*)lds;          // f = nt*5+ks
    const bf16x8* w2frag  = (const bf16x8*)lds + 2560;   // f = nt*4+ks
    const bf16x8* w1afrag = (const bf16x8*)lds + 4608;   // f = nt*4+ks
    short* stg   = lds  + 36864 + wave * 1280;           // [2][16][STG]
    float* baseF = ldsF + 28672 + wave * 512;            // [4][128]

    const int sb = (blockIdx.x & 7) * 32 + (blockIdx.x >> 3);
    const int node0 = sb * 64 + wave * 4;
    const int bidx = node0 >> 11;
    const float4* hb4 = (const float4*)h + (size_t)bidx * NPTS * 32;
    const float*  pb  = pos + (size_t)bidx * NPTS * 3;
    const int nloc = node0 & 2047;

    // neighbor indices for all 4 nodes (row m = lm)
    int idxv[4];
    #pragma unroll
    for (int ni = 0; ni < 4; ++ni)
        idxv[ni] = idx[(node0 + ni) * KNBR + lm];

    // ---- phase B: base = h_i . W1[0:128] + b1 via MFMA, spill to LDS ----
    {
        const float4* hsrc = hb4 + (size_t)(nloc + (lm & 3)) * 32;
        bf16x8 af[4];
        #pragma unroll
        for (int ks = 0; ks < 4; ++ks) {
            float4 p0 = hsrc[ks * 8 + quad * 2];
            float4 p1 = hsrc[ks * 8 + quad * 2 + 1];
            U8 t;
            t.u[0] = pk2(p0.x, p0.y); t.u[1] = pk2(p0.z, p0.w);
            t.u[2] = pk2(p1.x, p1.y); t.u[3] = pk2(p1.z, p1.w);
            af[ks] = t.v;
        }
        f32x4 bacc[8];
        #pragma unroll
        for (int nt = 0; nt < 8; ++nt)
            bacc[nt] = (f32x4){b1v[nt], b1v[nt], b1v[nt], b1v[nt]};
        #pragma unroll
        for (int ks = 0; ks < 4; ++ks)
            #pragma unroll
            for (int nt = 0; nt < 8; ++nt)
                bacc[nt] = __builtin_amdgcn_mfma_f32_16x16x32_bf16(
                    af[ks], w1afrag[(nt * 4 + ks) * 64 + lane], bacc[nt], 0, 0, 0);

        if (quad == 0)
            #pragma unroll
            for (int nt = 0; nt < 8; ++nt)
                #pragma unroll
                for (int r = 0; r < 4; ++r)
                    baseF[r * 128 + nt * 16 + lm] = bacc[nt][r];
    }
    __syncthreads();    // staging (layer-1) overlays w1a beyond this point

    // ---- pair loop: 2 nodes share every weight-fragment read ----
    #pragma unroll
    for (int pr = 0; pr < 2; ++pr) {
        const int na = pr * 2, nb = pr * 2 + 1;
        const int ja = idxv[na], jb = idxv[nb];

        // A-fragments (h_j - h_i), loads issued directly (R4-proven style)
        bf16x8 afA[4], afB[4];
        U8 rlA, rlB;
        {
            const float4* hiA4 = hb4 + (size_t)(nloc + na) * 32;
            const float4* hiB4 = hb4 + (size_t)(nloc + nb) * 32;
            const float4* hjA4 = hb4 + (size_t)ja * 32;
            const float4* hjB4 = hb4 + (size_t)jb * 32;
            #pragma unroll
            for (int ks = 0; ks < 4; ++ks) {
                float4 a0 = hiA4[ks * 8 + quad * 2];
                float4 a1 = hiA4[ks * 8 + quad * 2 + 1];
                float4 j0 = hjA4[ks * 8 + quad * 2];
                float4 j1 = hjA4[ks * 8 + quad * 2 + 1];
                U8 t;
                t.u[0] = pk2(j0.x - a0.x, j0.y - a0.y);
                t.u[1] = pk2(j0.z - a0.z, j0.w - a0.w);
                t.u[2] = pk2(j1.x - a1.x, j1.y - a1.y);
                t.u[3] = pk2(j1.z - a1.z, j1.w - a1.w);
                afA[ks] = t.v;
                float4 b0 = hiB4[ks * 8 + quad * 2];
                float4 b1_ = hiB4[ks * 8 + quad * 2 + 1];
                float4 k0 = hjB4[ks * 8 + quad * 2];
                float4 k1 = hjB4[ks * 8 + quad * 2 + 1];
                t.u[0] = pk2(k0.x - b0.x, k0.y - b0.y);
                t.u[1] = pk2(k0.z - b0.z, k0.w - b0.w);
                t.u[2] = pk2(k1.x - b1_.x, k1.y - b1_.y);
                t.u[3] = pk2(k1.z - b1_.z, k1.w - b1_.w);
                afB[ks] = t.v;
            }
            rlA.u[0] = 0; rlA.u[1] = 0; rlA.u[2] = 0; rlA.u[3] = 0;
            rlB.u[0] = 0; rlB.u[1] = 0; rlB.u[2] = 0; rlB.u[3] = 0;
            if (quad == 0) {
                int ia = nloc + na, ib = nloc + nb;
                rlA.u[0] = pk2(pb[3*ja]   - pb[3*ia],   pb[3*ja+1] - pb[3*ia+1]);
                rlA.u[1] = pk2(pb[3*ja+2] - pb[3*ia+2], 0.f);
                rlB.u[0] = pk2(pb[3*jb]   - pb[3*ib],   pb[3*jb+1] - pb[3*ib+1]);
                rlB.u[1] = pk2(pb[3*jb+2] - pb[3*ib+2], 0.f);
            }
        }

        // layer 1, 32-col chunks; immediate LDS re-read as layer-2 A-frags
        bf16x8 a2A[4], a2B[4];
        #pragma unroll
        for (int ks2 = 0; ks2 < 4; ++ks2) {
            #pragma unroll
            for (int ntl = 0; ntl < 2; ++ntl) {
                const int nt = ks2 * 2 + ntl;
                float bA = baseF[na * 128 + nt * 16 + lm];
                float bB = baseF[nb * 128 + nt * 16 + lm];
                f32x4 cA = (f32x4){bA, bA, bA, bA};
                f32x4 cB = (f32x4){bB, bB, bB, bB};
                #pragma unroll
                for (int ks = 0; ks < 4; ++ks) {
                    bf16x8 w = w1frag[(nt * 5 + ks) * 64 + lane];
                    cA = __builtin_amdgcn_mfma_f32_16x16x32_bf16(afA[ks], w, cA, 0, 0, 0);
                    cB = __builtin_amdgcn_mfma_f32_16x16x32_bf16(afB[ks], w, cB, 0, 0, 0);
                }
                {
                    bf16x8 w = w1frag[(nt * 5 + 4) * 64 + lane];
                    cA = __builtin_amdgcn_mfma_f32_16x16x32_bf16(rlA.v, w, cA, 0, 0, 0);
                    cB = __builtin_amdgcn_mfma_f32_16x16x32_bf16(rlB.v, w, cB, 0, 0, 0);
                }
                #pragma unroll
                for (int r = 0; r < 4; ++r) {
                    float gA = gelu(cA[r]), gB = gelu(cB[r]);
                    stg[      (quad * 4 + r) * STG + ntl * 16 + lm] = (short)pk2(gA, gA);
                    stg[640 + (quad * 4 + r) * STG + ntl * 16 + lm] = (short)pk2(gB, gB);
                }
            }
            asm volatile("s_waitcnt lgkmcnt(0)" ::: "memory");
            a2A[ks2] = *(const bf16x8*)(stg +       lm * STG + quad * 8);
            a2B[ks2] = *(const bf16x8*)(stg + 640 + lm * STG + quad * 8);
            asm volatile("s_waitcnt lgkmcnt(0)" ::: "memory");
        }

        // layer 2 (shared W2 reads) + max/min epilogue
        float vA[8], vB[8];
        #pragma unroll
        for (int nt = 0; nt < 8; ++nt) {
            f32x4 cA = (f32x4){0.f, 0.f, 0.f, 0.f};
            f32x4 cB = (f32x4){0.f, 0.f, 0.f, 0.f};
            #pragma unroll
            for (int ks = 0; ks < 4; ++ks) {
                bf16x8 w = w2frag[(nt * 4 + ks) * 64 + lane];
                cA = __builtin_amdgcn_mfma_f32_16x16x32_bf16(a2A[ks], w, cA, 0, 0, 0);
                cB = __builtin_amdgcn_mfma_f32_16x16x32_bf16(a2B[ks], w, cB, 0, 0, 0);
            }
            float mxA = fmaxf(fmaxf(cA[0], cA[1]), fmaxf(cA[2], cA[3]));
            float mnA = fminf(fminf(cA[0], cA[1]), fminf(cA[2], cA[3]));
            float mxB = fmaxf(fmaxf(cB[0], cB[1]), fmaxf(cB[2], cB[3]));
            float mnB = fminf(fminf(cB[0], cB[1]), fminf(cB[2], cB[3]));
            mxA = fmaxf(mxA, __shfl_xor(mxA, 16, 64));
            mxA = fmaxf(mxA, __shfl_xor(mxA, 32, 64));
            mnA = fminf(mnA, __shfl_xor(mnA, 16, 64));
            mnA = fminf(mnA, __shfl_xor(mnA, 32, 64));
            mxB = fmaxf(mxB, __shfl_xor(mxB, 16, 64));
            mxB = fmaxf(mxB, __shfl_xor(mxB, 32, 64));
            mnB = fminf(mnB, __shfl_xor(mnB, 16, 64));
            mnB = fminf(mnB, __shfl_xor(mnB, 32, 64));
            vA[nt] = fmaxf(gelu(mxA + b2v[nt]), gelu(mnA + b2v[nt]));
            vB[nt] = fmaxf(gelu(mxB + b2v[nt]), gelu(mnB + b2v[nt]));
        }

        // layernorm + store, both nodes
        #pragma unroll
        for (int u = 0; u < 2; ++u) {
            const float* v = u ? vB : vA;
            float s = 0.f, s2 = 0.f;
            #pragma unroll
            for (int nt = 0; nt < 8; ++nt) { s += v[nt]; s2 += v[nt] * v[nt]; }
            #pragma unroll
            for (int off = 1; off <= 8; off <<= 1) {
                s  += __shfl_xor(s,  off, 64);
                s2 += __shfl_xor(s2, off, 64);
            }
            const float mu  = s * (1.0f / 128.0f);
            const float var = s2 * (1.0f / 128.0f) - mu * mu;
            const float inv = rsqrtf(var + 1e-5f);
            float* orow = out + (size_t)(node0 + pr * 2 + u) * 128;
            orow[(quad * 2) * 16 + lm]     = (v[quad * 2]     - mu) * inv * gv0 + be0;
            orow[(quad * 2 + 1) * 16 + lm] = (v[quad * 2 + 1] - mu) * inv * gv1 + be1;
        }
    }
}

extern "C" void kernel_launch(void* const* d_in, const int* in_sizes, int n_in,
                              void* d_out, int out_size, void* d_ws, size_t ws_size,
                              hipStream_t stream) {
    const float* h     = (const float*)d_in[0];
    const float* pos   = (const float*)d_in[1];
    const int*   idx   = (const int*)  d_in[2];
    const float* W1    = (const float*)d_in[3];
    const float* b1    = (const float*)d_in[4];
    const float* W2    = (const float*)d_in[5];
    const float* b2    = (const float*)d_in[6];
    const float* gamma = (const float*)d_in[7];
    const float* beta  = (const float*)d_in[8];
    float* out = (float*)d_out;

    hipFuncSetAttribute((const void*)edgeconv_fused,
                        hipFuncAttributeMaxDynamicSharedMemorySize, LDS_BYTES);
    edgeconv_fused<<<256, 1024, LDS_BYTES, stream>>>(
        h, pos, idx, W1, W2, b1, b2, gamma, beta, out);
}

// Round 9
// 119.860 us; speedup vs baseline: 1.0493x; 1.0493x over previous
//
#include <hip/hip_runtime.h>

#define NPTS 2048
#define KNBR 16

typedef __attribute__((ext_vector_type(8))) short bf16x8;
typedef __attribute__((ext_vector_type(4))) float f32x4;
union U8 { bf16x8 v; unsigned u[4]; };

// gfx950 packed f32->bf16 (RNE)
static __device__ __forceinline__ unsigned pk2(float lo, float hi) {
    unsigned r;
    asm("v_cvt_pk_bf16_f32 %0, %1, %2" : "=v"(r) : "v"(lo), "v"(hi));
    return r;
}

// tanh-approx gelu (sigmoid form) — R5/R8-proven __expf variant
static __device__ __forceinline__ float gelu(float x) {
    float x2 = x * x;
    float u  = x * fmaf(x2, 0.044715f, 1.0f);
    float e  = __expf(u * -1.5957691216057308f);
    return x * __builtin_amdgcn_rcpf(1.0f + e);
}

// LDS layout (shorts) — byte-identical to R8 except w1a -> w1d contents:
//   [0,20480)      w1f : W1 rows 128..287 (5 ks, rows>=259 zero), f=nt*5+ks
//   [20480,36864)  w2f : W2 (4 ks), f=nt*4+ks
//   [36864,53248)  w1d : (W1 rows 0..127) - (W1 rows 128..255), phase-B only
//   [36864,57344)  staging (overlays w1d after barrier):
//                  16 waves x [2 nodes][16 m][STG=40]
//   [57344,73728)  base: 16 waves x 4 nodes x 128 fp32
#define STG 40
#define LDS_BYTES 147456

__global__ __launch_bounds__(1024, 4) void edgeconv_fused(
    const float* __restrict__ h, const float* __restrict__ pos,
    const int* __restrict__ idx,
    const float* __restrict__ W1, const float* __restrict__ W2,
    const float* __restrict__ b1, const float* __restrict__ b2,
    const float* __restrict__ gamma, const float* __restrict__ beta,
    float* __restrict__ out)
{
    extern __shared__ short lds[];
    float* ldsF = (float*)lds;
    const int tid = threadIdx.x, wave = tid >> 6, lane = tid & 63;
    const int quad = lane >> 4, lm = lane & 15;

    // ---- phase A: swizzle weights (global fp32 -> LDS bf16 B-fragments) ----
    for (int c = tid; c < 6656; c += 1024) {
        const int l = c & 63, fi = c >> 6;
        const int lrow = (l >> 4) * 8, lcol = l & 15;
        U8 t;
        if (fi < 40) {                        // w1f = W1b (rows 128..287)
            int ks = fi % 5, nt = fi / 5;
            int row0 = 128 + ks * 32 + lrow, col = nt * 16 + lcol;
            #pragma unroll
            for (int p = 0; p < 4; ++p) {
                int r0 = row0 + 2 * p;
                float v0 = (r0     < 259) ? W1[r0 * 128 + col]       : 0.f;
                float v1 = (r0 + 1 < 259) ? W1[(r0 + 1) * 128 + col] : 0.f;
                t.u[p] = pk2(v0, v1);
            }
        } else if (fi < 72) {                 // w2f
            int f2 = fi - 40, ks = f2 & 3, nt = f2 >> 2;
            int row0 = ks * 32 + lrow, col = nt * 16 + lcol;
            #pragma unroll
            for (int p = 0; p < 4; ++p)
                t.u[p] = pk2(W2[(row0 + 2*p) * 128 + col],
                             W2[(row0 + 2*p + 1) * 128 + col]);
        } else {                              // w1d = W1a - W1b (rows 0..127)
            int f2 = fi - 72, ks = f2 & 3, nt = f2 >> 2;
            int row0 = ks * 32 + lrow, col = nt * 16 + lcol;
            #pragma unroll
            for (int p = 0; p < 4; ++p) {
                int r0 = row0 + 2 * p;
                float v0 = W1[r0 * 128 + col]       - W1[(r0 + 128) * 128 + col];
                float v1 = W1[(r0 + 1) * 128 + col] - W1[(r0 + 129) * 128 + col];
                t.u[p] = pk2(v0, v1);
            }
        }
        ((bf16x8*)lds)[c] = t.v;
    }

    float b1v[8], b2v[8];
    #pragma unroll
    for (int nt = 0; nt < 8; ++nt) {
        b1v[nt] = b1[nt * 16 + lm];
        b2v[nt] = b2[nt * 16 + lm];
    }
    const float gv0 = gamma[(quad * 2) * 16 + lm];
    const float gv1 = gamma[(quad * 2 + 1) * 16 + lm];
    const float be0 = beta[(quad * 2) * 16 + lm];
    const float be1 = beta[(quad * 2 + 1) * 16 + lm];

    __syncthreads();

    const bf16x8* w1frag  = (const bf16x8*)lds;          // W1b, f = nt*5+ks
    const bf16x8* w2frag  = (const bf16x8*)lds + 2560;   // f = nt*4+ks
    const bf16x8* w1dfrag = (const bf16x8*)lds + 4608;   // W1d, f = nt*4+ks
    short* stg   = lds  + 36864 + wave * 1280;           // [2][16][STG]
    float* baseF = ldsF + 28672 + wave * 512;            // [4][128]

    const int sb = (blockIdx.x & 7) * 32 + (blockIdx.x >> 3);
    const int node0 = sb * 64 + wave * 4;
    const int bidx = node0 >> 11;
    const float4* hb4 = (const float4*)h + (size_t)bidx * NPTS * 32;
    const float*  pb  = pos + (size_t)bidx * NPTS * 3;
    const int nloc = node0 & 2047;

    int idxv[4];
    #pragma unroll
    for (int ni = 0; ni < 4; ++ni)
        idxv[ni] = idx[(node0 + ni) * KNBR + lm];

    // ---- phase B: base = h_i . W1d + b1 via MFMA, spill to LDS ----
    {
        const float4* hsrc = hb4 + (size_t)(nloc + (lm & 3)) * 32;
        bf16x8 af[4];
        #pragma unroll
        for (int ks = 0; ks < 4; ++ks) {
            float4 p0 = hsrc[ks * 8 + quad * 2];
            float4 p1 = hsrc[ks * 8 + quad * 2 + 1];
            U8 t;
            t.u[0] = pk2(p0.x, p0.y); t.u[1] = pk2(p0.z, p0.w);
            t.u[2] = pk2(p1.x, p1.y); t.u[3] = pk2(p1.z, p1.w);
            af[ks] = t.v;
        }
        f32x4 bacc[8];
        #pragma unroll
        for (int nt = 0; nt < 8; ++nt)
            bacc[nt] = (f32x4){b1v[nt], b1v[nt], b1v[nt], b1v[nt]};
        #pragma unroll
        for (int ks = 0; ks < 4; ++ks)
            #pragma unroll
            for (int nt = 0; nt < 8; ++nt)
                bacc[nt] = __builtin_amdgcn_mfma_f32_16x16x32_bf16(
                    af[ks], w1dfrag[(nt * 4 + ks) * 64 + lane], bacc[nt], 0, 0, 0);

        if (quad == 0)
            #pragma unroll
            for (int nt = 0; nt < 8; ++nt)
                #pragma unroll
                for (int r = 0; r < 4; ++r)
                    baseF[r * 128 + nt * 16 + lm] = bacc[nt][r];
    }
    __syncthreads();    // staging overlays w1d beyond this point

    // ---- pair loop ----
    #pragma unroll
    for (int pr = 0; pr < 2; ++pr) {
        const int na = pr * 2, nb = pr * 2 + 1;
        const int ja = idxv[na], jb = idxv[nb];

        // A-fragments = bf16(h_j) directly (W1d trick: no h_i loads, no subs)
        bf16x8 afA[4], afB[4];
        U8 rlA, rlB;
        {
            const float4* hjA4 = hb4 + (size_t)ja * 32;
            const float4* hjB4 = hb4 + (size_t)jb * 32;
            #pragma unroll
            for (int ks = 0; ks < 4; ++ks) {
                float4 j0 = hjA4[ks * 8 + quad * 2];
                float4 j1 = hjA4[ks * 8 + quad * 2 + 1];
                U8 t;
                t.u[0] = pk2(j0.x, j0.y); t.u[1] = pk2(j0.z, j0.w);
                t.u[2] = pk2(j1.x, j1.y); t.u[3] = pk2(j1.z, j1.w);
                afA[ks] = t.v;
                float4 k0 = hjB4[ks * 8 + quad * 2];
                float4 k1 = hjB4[ks * 8 + quad * 2 + 1];
                t.u[0] = pk2(k0.x, k0.y); t.u[1] = pk2(k0.z, k0.w);
                t.u[2] = pk2(k1.x, k1.y); t.u[3] = pk2(k1.z, k1.w);
                afB[ks] = t.v;
            }
            rlA.u[0] = 0; rlA.u[1] = 0; rlA.u[2] = 0; rlA.u[3] = 0;
            rlB.u[0] = 0; rlB.u[1] = 0; rlB.u[2] = 0; rlB.u[3] = 0;
            if (quad == 0) {
                int ia = nloc + na, ib = nloc + nb;
                rlA.u[0] = pk2(pb[3*ja]   - pb[3*ia],   pb[3*ja+1] - pb[3*ia+1]);
                rlA.u[1] = pk2(pb[3*ja+2] - pb[3*ia+2], 0.f);
                rlB.u[0] = pk2(pb[3*jb]   - pb[3*ib],   pb[3*jb+1] - pb[3*ib+1]);
                rlB.u[1] = pk2(pb[3*jb+2] - pb[3*ib+2], 0.f);
            }
        }

        // layer 1, 32-col chunks; immediate LDS re-read as layer-2 A-frags
        bf16x8 a2A[4], a2B[4];
        #pragma unroll
        for (int ks2 = 0; ks2 < 4; ++ks2) {
            #pragma unroll
            for (int ntl = 0; ntl < 2; ++ntl) {
                const int nt = ks2 * 2 + ntl;
                float bA = baseF[na * 128 + nt * 16 + lm];
                float bB = baseF[nb * 128 + nt * 16 + lm];
                f32x4 cA = (f32x4){bA, bA, bA, bA};
                f32x4 cB = (f32x4){bB, bB, bB, bB};
                #pragma unroll
                for (int ks = 0; ks < 4; ++ks) {
                    bf16x8 w = w1frag[(nt * 5 + ks) * 64 + lane];
                    cA = __builtin_amdgcn_mfma_f32_16x16x32_bf16(afA[ks], w, cA, 0, 0, 0);
                    cB = __builtin_amdgcn_mfma_f32_16x16x32_bf16(afB[ks], w, cB, 0, 0, 0);
                }
                {
                    bf16x8 w = w1frag[(nt * 5 + 4) * 64 + lane];
                    cA = __builtin_amdgcn_mfma_f32_16x16x32_bf16(rlA.v, w, cA, 0, 0, 0);
                    cB = __builtin_amdgcn_mfma_f32_16x16x32_bf16(rlB.v, w, cB, 0, 0, 0);
                }
                #pragma unroll
                for (int r = 0; r < 4; ++r) {
                    float gA = gelu(cA[r]), gB = gelu(cB[r]);
                    stg[      (quad * 4 + r) * STG + ntl * 16 + lm] = (short)pk2(gA, gA);
                    stg[640 + (quad * 4 + r) * STG + ntl * 16 + lm] = (short)pk2(gB, gB);
                }
            }
            asm volatile("s_waitcnt lgkmcnt(0)" ::: "memory");
            a2A[ks2] = *(const bf16x8*)(stg +       lm * STG + quad * 8);
            a2B[ks2] = *(const bf16x8*)(stg + 640 + lm * STG + quad * 8);
            asm volatile("s_waitcnt lgkmcnt(0)" ::: "memory");
        }

        // layer 2 + max/min epilogue
        float vA[8], vB[8];
        #pragma unroll
        for (int nt = 0; nt < 8; ++nt) {
            f32x4 cA = (f32x4){0.f, 0.f, 0.f, 0.f};
            f32x4 cB = (f32x4){0.f, 0.f, 0.f, 0.f};
            #pragma unroll
            for (int ks = 0; ks < 4; ++ks) {
                bf16x8 w = w2frag[(nt * 4 + ks) * 64 + lane];
                cA = __builtin_amdgcn_mfma_f32_16x16x32_bf16(a2A[ks], w, cA, 0, 0, 0);
                cB = __builtin_amdgcn_mfma_f32_16x16x32_bf16(a2B[ks], w, cB, 0, 0, 0);
            }
            float mxA = fmaxf(fmaxf(cA[0], cA[1]), fmaxf(cA[2], cA[3]));
            float mnA = fminf(fminf(cA[0], cA[1]), fminf(cA[2], cA[3]));
            float mxB = fmaxf(fmaxf(cB[0], cB[1]), fmaxf(cB[2], cB[3]));
            float mnB = fminf(fminf(cB[0], cB[1]), fminf(cB[2], cB[3]));
            mxA = fmaxf(mxA, __shfl_xor(mxA, 16, 64));
            mxA = fmaxf(mxA, __shfl_xor(mxA, 32, 64));
            mnA = fminf(mnA, __shfl_xor(mnA, 16, 64));
            mnA = fminf(mnA, __shfl_xor(mnA, 32, 64));
            mxB = fmaxf(mxB, __shfl_xor(mxB, 16, 64));
            mxB = fmaxf(mxB, __shfl_xor(mxB, 32, 64));
            mnB = fminf(mnB, __shfl_xor(mnB, 16, 64));
            mnB = fminf(mnB, __shfl_xor(mnB, 32, 64));
            vA[nt] = fmaxf(gelu(mxA + b2v[nt]), gelu(mnA + b2v[nt]));
            vB[nt] = fmaxf(gelu(mxB + b2v[nt]), gelu(mnB + b2v[nt]));
        }

        // layernorm + store
        #pragma unroll
        for (int u = 0; u < 2; ++u) {
            const float* v = u ? vB : vA;
            float s = 0.f, s2 = 0.f;
            #pragma unroll
            for (int nt = 0; nt < 8; ++nt) { s += v[nt]; s2 += v[nt] * v[nt]; }
            #pragma unroll
            for (int off = 1; off <= 8; off <<= 1) {
                s  += __shfl_xor(s,  off, 64);
                s2 += __shfl_xor(s2, off, 64);
            }
            const float mu  = s * (1.0f / 128.0f);
            const float var = s2 * (1.0f / 128.0f) - mu * mu;
            const float inv = rsqrtf(var + 1e-5f);
            float* orow = out + (size_t)(node0 + pr * 2 + u) * 128;
            orow[(quad * 2) * 16 + lm]     = (v[quad * 2]     - mu) * inv * gv0 + be0;
            orow[(quad * 2 + 1) * 16 + lm] = (v[quad * 2 + 1] - mu) * inv * gv1 + be1;
        }
    }
}

extern "C" void kernel_launch(void* const* d_in, const int* in_sizes, int n_in,
                              void* d_out, int out_size, void* d_ws, size_t ws_size,
                              hipStream_t stream) {
    const float* h     = (const float*)d_in[0];
    const float* pos   = (const float*)d_in[1];
    const int*   idx   = (const int*)  d_in[2];
    const float* W1    = (const float*)d_in[3];
    const float* b1    = (const float*)d_in[4];
    const float* W2    = (const float*)d_in[5];
    const float* b2    = (const float*)d_in[6];
    const float* gamma = (const float*)d_in[7];
    const float* beta  = (const float*)d_in[8];
    float* out = (float*)d_out;

    hipFuncSetAttribute((const void*)edgeconv_fused,
                        hipFuncAttributeMaxDynamicSharedMemorySize, LDS_BYTES);
    edgeconv_fused<<<256, 1024, LDS_BYTES, stream>>>(
        h, pos, idx, W1, W2, b1, b2, gamma, beta, out);
}